// Round 5
// baseline (518.514 us; speedup 1.0000x reference)
//
#include <hip/hip_runtime.h>
#include <hip/hip_bf16.h>

#define B_ 16384
#define F_ 128
#define D_ 256
#define A_ 256
#define T_ 64
#define DECAY_ 0.9f
#define SCALE2 2.885390081777927f   // 2*log2(e)
#define L2E    1.4426950408889634f  // log2(e)

typedef __attribute__((ext_vector_type(8))) __bf16 bf16x8;
typedef __attribute__((ext_vector_type(4))) float f32x4;

#if __has_builtin(__builtin_amdgcn_exp2f)
#define EXP2(x) __builtin_amdgcn_exp2f(x)
#else
#define EXP2(x) exp2f(x)
#endif
#define RCP(x) __builtin_amdgcn_rcpf(x)

__device__ __forceinline__ float tanh2(float x) {
    float e = EXP2(SCALE2 * x);
    return 1.0f - 2.0f * RCP(e + 1.0f);
}
__device__ __forceinline__ float sigmoid2(float x) {
    float e = EXP2(-L2E * x);
    return RCP(1.0f + e);
}
__device__ __forceinline__ bool get_mask(const void* mp, int mflag, int row) {
    if (mflag) return ((const unsigned char*)mp)[row] != 0;
    return ((const int*)mp)[row] != 0;
}
__device__ __forceinline__ unsigned short bfbits(float f) {
    __bf16 h = (__bf16)f;
    return __builtin_bit_cast(unsigned short, h);
}
__device__ __forceinline__ float bits2f(unsigned short u) {
    return __builtin_bit_cast(float, ((unsigned)u) << 16);
}

// ---- mask dtype probe ----
__global__ __launch_bounds__(256) void mask_probe(const unsigned int* m, int* flag) {
    __shared__ int f;
    if (threadIdx.x == 0) f = 0;
    __syncthreads();
    int any = 0;
    for (int i = threadIdx.x; i < B_ / 4; i += 256) any |= (m[i] > 1u) ? 1 : 0;
    if (any) atomicOr(&f, 1);
    __syncthreads();
    if (threadIdx.x == 0) flag[0] = f;
}

// ---- convert weights fp32 -> bf16 row-major ----
__global__ __launch_bounds__(256) void convert_w(const float* Wih, const float* Whh, const float* Wc,
                                                 __bf16* Wihb, __bf16* Whhb, __bf16* Wcb) {
    const int n1 = 768 * 128, n2 = n1 + 768 * 256, n3 = n2 + 256 * 256;
    int i = (blockIdx.x * 256 + threadIdx.x) * 4;
    if (i < n1) {
#pragma unroll
        for (int j = 0; j < 4; ++j) Wihb[i + j] = (__bf16)Wih[i + j];
    } else if (i < n2) {
        int k = i - n1;
#pragma unroll
        for (int j = 0; j < 4; ++j) Whhb[k + j] = (__bf16)Whh[k + j];
    } else if (i < n3) {
        int k = i - n2;
#pragma unroll
        for (int j = 0; j < 4; ++j) Wcb[k + j] = (__bf16)Wc[k + j];
    }
}

// ---- histf = tanh(tokens) f32 [T,D]; tokpb = SCALE2*(hist @ Wh.T + bh) bf16 [T,A] ----
__global__ __launch_bounds__(256) void prep_kernel(const float* tokens, const float* Wh, const float* bh,
                                                   float* histf, __bf16* tokpb) {
    int t = blockIdx.x, tid = threadIdx.x;
    __shared__ float hrow[D_];
    float hv = tanh2(tokens[t * D_ + tid]);
    hrow[tid] = hv;
    histf[t * D_ + tid] = hv;
    __syncthreads();
    float acc = bh[tid];
    const float* wr = &Wh[tid * D_];
    for (int d = 0; d < D_; d++) acc += hrow[d] * wr[d];
    tokpb[t * A_ + tid] = (__bf16)(acc * SCALE2);
}

// ---- fused GRU (MFMA, nt-split for occupancy) + ctx GEMM ----
#define XS 392   // shorts/row: 384 + 8 pad
#define HS 264   // shorts/row: 256 + 8 pad
__global__ __launch_bounds__(256, 4) void gru_fused(
    const float* __restrict__ features, const float* __restrict__ h,
    const void* maskp, const int* __restrict__ mflagp,
    const __bf16* __restrict__ Wihb, const __bf16* __restrict__ Whhb, const __bf16* __restrict__ Wcb,
    const float* __restrict__ b_ih, const float* __restrict__ b_hh, const float* __restrict__ bcp,
    float* __restrict__ hout, __bf16* __restrict__ ctxb)
{
    __shared__ __bf16 Xs[32 * XS];
    __shared__ __bf16 Hn[32 * HS];
    int tid = threadIdx.x;
    int b0 = blockIdx.x * 32;
    int wv = tid >> 6, lane = tid & 63;
    int lan15 = lane & 15, kg = lane >> 4;
    int klo = kg * 8;
    int dsl = wv * 64;
    int mflag = mflagp[0];

#pragma unroll
    for (int it = 0; it < 4; ++it) {
        int idx = (it * 256 + tid) * 4;
        int r = idx >> 7, c = idx & 127;
        float4 vv = *(const float4*)&features[(size_t)(b0 + r) * F_ + c];
        ushort4 w = { bfbits(vv.x), bfbits(vv.y), bfbits(vv.z), bfbits(vv.w) };
        *reinterpret_cast<ushort4*>(&Xs[r * XS + c]) = w;
    }
#pragma unroll
    for (int it = 0; it < 8; ++it) {
        int idx = (it * 256 + tid) * 4;
        int r = idx >> 8, c = idx & 255;
        float4 vv = *(const float4*)&h[(size_t)(b0 + r) * D_ + c];
        ushort4 w = { bfbits(vv.x), bfbits(vv.y), bfbits(vv.z), bfbits(vv.w) };
        *reinterpret_cast<ushort4*>(&Xs[r * XS + 128 + c]) = w;
    }
    // mask bits for this thread's 8 rows (mt*16 + kg*4 + rg)
    unsigned mbits = 0;
#pragma unroll
    for (int mt = 0; mt < 2; ++mt)
#pragma unroll
        for (int rg = 0; rg < 4; ++rg) {
            int row = mt * 16 + kg * 4 + rg;
            if (get_mask(maskp, mflag, b0 + row)) mbits |= 1u << (mt * 4 + rg);
        }
    __syncthreads();

    // two N-passes over nt pairs: acc live = 64 f32 -> 4 waves/SIMD
#pragma unroll
    for (int np = 0; np < 2; ++np) {
        f32x4 ar[2][2] = {}, az[2][2] = {}, ai[2][2] = {}, ah[2][2] = {};
#pragma unroll
        for (int kb = 0; kb < 4; ++kb) {
            bf16x8 a0 = *reinterpret_cast<const bf16x8*>(&Xs[lan15 * XS + kb * 32 + klo]);
            bf16x8 a1 = *reinterpret_cast<const bf16x8*>(&Xs[(16 + lan15) * XS + kb * 32 + klo]);
#pragma unroll
            for (int ntl = 0; ntl < 2; ++ntl) {
                int nt = np * 2 + ntl;
                const __bf16* p = Wihb + (size_t)(dsl + nt * 16 + lan15) * F_ + kb * 32 + klo;
                bf16x8 br = *reinterpret_cast<const bf16x8*>(p);
                bf16x8 bz = *reinterpret_cast<const bf16x8*>(p + 256 * F_);
                bf16x8 bn = *reinterpret_cast<const bf16x8*>(p + 512 * F_);
                ar[0][ntl] = __builtin_amdgcn_mfma_f32_16x16x32_bf16(a0, br, ar[0][ntl], 0, 0, 0);
                ar[1][ntl] = __builtin_amdgcn_mfma_f32_16x16x32_bf16(a1, br, ar[1][ntl], 0, 0, 0);
                az[0][ntl] = __builtin_amdgcn_mfma_f32_16x16x32_bf16(a0, bz, az[0][ntl], 0, 0, 0);
                az[1][ntl] = __builtin_amdgcn_mfma_f32_16x16x32_bf16(a1, bz, az[1][ntl], 0, 0, 0);
                ai[0][ntl] = __builtin_amdgcn_mfma_f32_16x16x32_bf16(a0, bn, ai[0][ntl], 0, 0, 0);
                ai[1][ntl] = __builtin_amdgcn_mfma_f32_16x16x32_bf16(a1, bn, ai[1][ntl], 0, 0, 0);
            }
        }
#pragma unroll
        for (int kb = 0; kb < 8; ++kb) {
            bf16x8 a0 = *reinterpret_cast<const bf16x8*>(&Xs[lan15 * XS + 128 + kb * 32 + klo]);
            bf16x8 a1 = *reinterpret_cast<const bf16x8*>(&Xs[(16 + lan15) * XS + 128 + kb * 32 + klo]);
#pragma unroll
            for (int ntl = 0; ntl < 2; ++ntl) {
                int nt = np * 2 + ntl;
                const __bf16* p = Whhb + (size_t)(dsl + nt * 16 + lan15) * D_ + kb * 32 + klo;
                bf16x8 br = *reinterpret_cast<const bf16x8*>(p);
                bf16x8 bz = *reinterpret_cast<const bf16x8*>(p + 256 * D_);
                bf16x8 bn = *reinterpret_cast<const bf16x8*>(p + 512 * D_);
                ar[0][ntl] = __builtin_amdgcn_mfma_f32_16x16x32_bf16(a0, br, ar[0][ntl], 0, 0, 0);
                ar[1][ntl] = __builtin_amdgcn_mfma_f32_16x16x32_bf16(a1, br, ar[1][ntl], 0, 0, 0);
                az[0][ntl] = __builtin_amdgcn_mfma_f32_16x16x32_bf16(a0, bz, az[0][ntl], 0, 0, 0);
                az[1][ntl] = __builtin_amdgcn_mfma_f32_16x16x32_bf16(a1, bz, az[1][ntl], 0, 0, 0);
                ah[0][ntl] = __builtin_amdgcn_mfma_f32_16x16x32_bf16(a0, bn, ah[0][ntl], 0, 0, 0);
                ah[1][ntl] = __builtin_amdgcn_mfma_f32_16x16x32_bf16(a1, bn, ah[1][ntl], 0, 0, 0);
            }
        }
        // epilogue for this nt pair
#pragma unroll
        for (int ntl = 0; ntl < 2; ++ntl) {
            int nt = np * 2 + ntl;
            int d = dsl + nt * 16 + lan15;
            float brv = b_ih[d] + b_hh[d];
            float bzv = b_ih[256 + d] + b_hh[256 + d];
            float biv = b_ih[512 + d];
            float bhv = b_hh[512 + d];
#pragma unroll
            for (int mt = 0; mt < 2; ++mt)
#pragma unroll
                for (int rg = 0; rg < 4; ++rg) {
                    int row = mt * 16 + kg * 4 + rg;
                    float hv = (float)Xs[row * XS + 128 + d];
                    float rv = sigmoid2(ar[mt][ntl][rg] + brv);
                    float zv = sigmoid2(az[mt][ntl][rg] + bzv);
                    float nv = tanh2(ai[mt][ntl][rg] + biv + rv * (ah[mt][ntl][rg] + bhv));
                    float hn = (1.0f - zv) * nv + zv * hv;
                    Hn[row * HS + d] = (__bf16)hn;
                    bool m = (mbits >> (mt * 4 + rg)) & 1u;
                    hout[(size_t)(b0 + row) * D_ + d] = m ? hn : hv;
                }
        }
    }
    __syncthreads();

    // ctx = h_new @ Wc.T + bc, pre-scaled bf16 out
    f32x4 ac[2][4] = {};
#pragma unroll
    for (int kb = 0; kb < 8; ++kb) {
        bf16x8 a0 = *reinterpret_cast<const bf16x8*>(&Hn[lan15 * HS + kb * 32 + klo]);
        bf16x8 a1 = *reinterpret_cast<const bf16x8*>(&Hn[(16 + lan15) * HS + kb * 32 + klo]);
#pragma unroll
        for (int nt = 0; nt < 4; ++nt) {
            bf16x8 b = *reinterpret_cast<const bf16x8*>(&Wcb[(size_t)(dsl + nt * 16 + lan15) * D_ + kb * 32 + klo]);
            ac[0][nt] = __builtin_amdgcn_mfma_f32_16x16x32_bf16(a0, b, ac[0][nt], 0, 0, 0);
            ac[1][nt] = __builtin_amdgcn_mfma_f32_16x16x32_bf16(a1, b, ac[1][nt], 0, 0, 0);
        }
    }
#pragma unroll
    for (int mt = 0; mt < 2; ++mt)
#pragma unroll
        for (int rg = 0; rg < 4; ++rg) {
            int row = mt * 16 + kg * 4 + rg;
#pragma unroll
            for (int nt = 0; nt < 4; ++nt) {
                int d = dsl + nt * 16 + lan15;
                ctxb[(size_t)(b0 + row) * A_ + d] = (__bf16)((ac[mt][nt][rg] + bcp[d]) * SCALE2);
            }
        }
}

// ---- attention: 256 thr, 8 rows/block, 2 rows/wave; tokp staged in 2 halves (16KB LDS) ----
// score = sum_a -2*v_a * rcp(fma(exp2(tk), exp2(cc), 1))   [exp factored: 2 VALU + 1 trans /elem/row]
__global__ __launch_bounds__(256, 8) void attn5(
    const __bf16* __restrict__ ctxb, const __bf16* __restrict__ tokpb,
    const float* __restrict__ histf, const float* __restrict__ v,
    const float* __restrict__ accum, const void* maskp, const int* __restrict__ mflagp,
    float* __restrict__ out_emb)
{
    __shared__ __bf16 tls[32 * A_];   // 16KB: half of tokp~
    __shared__ float sls[8 * T_];     // 2KB scores/weights
    int tid = threadIdx.x;
    int b0 = blockIdx.x * 8;
    int wv = tid >> 6, lane = tid & 63;
    int al = lane & 31, th = lane >> 5;
    int mflag = mflagp[0];

    int a0 = al * 8;
    float vn[8];
    {
        float4 v0 = *(const float4*)&v[a0];
        float4 v1 = *(const float4*)&v[a0 + 4];
        vn[0] = -2.f * v0.x; vn[1] = -2.f * v0.y; vn[2] = -2.f * v0.z; vn[3] = -2.f * v0.w;
        vn[4] = -2.f * v1.x; vn[5] = -2.f * v1.y; vn[6] = -2.f * v1.z; vn[7] = -2.f * v1.w;
    }
    // ec[r][j] = exp2(ctx~)
    float ec[2][8];
#pragma unroll
    for (int r = 0; r < 2; ++r) {
        bf16x8 c8 = *(const bf16x8*)&ctxb[(size_t)(b0 + wv * 2 + r) * A_ + a0];
#pragma unroll
        for (int j = 0; j < 8; ++j) ec[r][j] = EXP2((float)c8[j]);
    }

#pragma unroll
    for (int half = 0; half < 2; ++half) {
        __syncthreads();   // previous-half readers done (no-op cost at half 0)
        for (int j = tid; j < 32 * A_ / 8; j += 256)
            ((uint4*)tls)[j] = ((const uint4*)(tokpb + half * 32 * A_))[j];
        __syncthreads();

        for (int tc = 0; tc < 16; ++tc) {
            int tl_ = tc * 2 + th;
            bf16x8 k8 = *(const bf16x8*)&tls[tl_ * A_ + a0];
            float p0 = 0.f, p1 = 0.f;
#pragma unroll
            for (int j = 0; j < 8; ++j) {
                float et = EXP2((float)k8[j]);
                p0 = fmaf(vn[j], RCP(fmaf(et, ec[0][j], 1.0f)), p0);
                p1 = fmaf(vn[j], RCP(fmaf(et, ec[1][j], 1.0f)), p1);
            }
#pragma unroll
            for (int m = 1; m < 32; m <<= 1) {
                p0 += __shfl_xor(p0, m, 64);
                p1 += __shfl_xor(p1, m, 64);
            }
            if (al == 0) {
                int t = half * 32 + tl_;
                sls[(wv * 2 + 0) * T_ + t] = p0;
                sls[(wv * 2 + 1) * T_ + t] = p1;
            }
        }
    }

    // softmax per row over T (intra-wave only: rows written by this wave)
#pragma unroll
    for (int r = 0; r < 2; ++r) {
        float x = sls[(wv * 2 + r) * T_ + lane];
        float mx = x;
#pragma unroll
        for (int m = 1; m < 64; m <<= 1) mx = fmaxf(mx, __shfl_xor(mx, m, 64));
        float e = EXP2(L2E * (x - mx));
        float s = e;
#pragma unroll
        for (int m = 1; m < 64; m <<= 1) s += __shfl_xor(s, m, 64);
        sls[(wv * 2 + r) * T_ + lane] = e * RCP(s);
    }

    // emb = weights @ hist ; hist read from L1/L2 (f32, 64KB table, cache-resident)
    int d0 = lane * 4;
    float acc4[2][4] = {};
    for (int t = 0; t < T_; ++t) {
        float4 h4 = *(const float4*)&histf[t * D_ + d0];
        float w0 = sls[(wv * 2 + 0) * T_ + t];
        float w1 = sls[(wv * 2 + 1) * T_ + t];
        acc4[0][0] = fmaf(w0, h4.x, acc4[0][0]); acc4[0][1] = fmaf(w0, h4.y, acc4[0][1]);
        acc4[0][2] = fmaf(w0, h4.z, acc4[0][2]); acc4[0][3] = fmaf(w0, h4.w, acc4[0][3]);
        acc4[1][0] = fmaf(w1, h4.x, acc4[1][0]); acc4[1][1] = fmaf(w1, h4.y, acc4[1][1]);
        acc4[1][2] = fmaf(w1, h4.z, acc4[1][2]); acc4[1][3] = fmaf(w1, h4.w, acc4[1][3]);
    }
#pragma unroll
    for (int r = 0; r < 2; ++r) {
        size_t row = (size_t)(b0 + wv * 2 + r);
        bool m = get_mask(maskp, mflag, (int)row);
        float4 av = *(const float4*)&accum[row * D_ + d0];
        float4 o;
        o.x = m ? fmaf(av.x, DECAY_, acc4[r][0]) : av.x;
        o.y = m ? fmaf(av.y, DECAY_, acc4[r][1]) : av.y;
        o.z = m ? fmaf(av.z, DECAY_, acc4[r][2]) : av.z;
        o.w = m ? fmaf(av.w, DECAY_, acc4[r][3]) : av.w;
        *(float4*)&out_emb[row * D_ + d0] = o;
    }
}

extern "C" void kernel_launch(void* const* d_in, const int* in_sizes, int n_in,
                              void* d_out, int out_size, void* d_ws, size_t ws_size,
                              hipStream_t stream) {
    const float* features = (const float*)d_in[0];
    const float* h        = (const float*)d_in[1];
    const float* accum    = (const float*)d_in[2];
    const void*  maskp    = d_in[3];
    const float* tokens   = (const float*)d_in[4];
    const float* Wih      = (const float*)d_in[5];
    const float* Whh      = (const float*)d_in[6];
    const float* bih      = (const float*)d_in[7];
    const float* bhh      = (const float*)d_in[8];
    const float* Wh       = (const float*)d_in[9];
    const float* bh       = (const float*)d_in[10];
    const float* Wc       = (const float*)d_in[11];
    const float* bc       = (const float*)d_in[12];
    const float* v        = (const float*)d_in[13];
    // d_in[14] = bv : softmax-invariant, unused

    float* out = (float*)d_out;  // [B*D] emb_out, then [B*D] h_out

    __bf16* Wihb  = (__bf16*)d_ws;                  // 768*128
    __bf16* Whhb  = Wihb + 768 * 128;               // 768*256
    __bf16* Wcb   = Whhb + 768 * 256;               // 256*256
    __bf16* tokpb = Wcb + 256 * 256;                // 64*256 (pre-scaled)
    float*  histf = (float*)(tokpb + 64 * 256);     // 64*256 f32
    __bf16* ctxb  = (__bf16*)(histf + 64 * 256);    // B*256 (pre-scaled)
    int*    mflag = (int*)(ctxb + (size_t)B_ * D_);

    hipLaunchKernelGGL(mask_probe, dim3(1), dim3(256), 0, stream,
                       (const unsigned int*)maskp, mflag);
    hipLaunchKernelGGL(convert_w, dim3(352), dim3(256), 0, stream,
                       Wih, Whh, Wc, Wihb, Whhb, Wcb);
    hipLaunchKernelGGL(prep_kernel, dim3(64), dim3(256), 0, stream,
                       tokens, Wh, bh, histf, tokpb);
    hipLaunchKernelGGL(gru_fused, dim3(B_ / 32), dim3(256), 0, stream,
                       features, h, maskp, mflag, Wihb, Whhb, Wcb, bih, bhh, bc,
                       out + (size_t)B_ * D_, ctxb);
    hipLaunchKernelGGL(attn5, dim3(B_ / 8), dim3(256), 0, stream,
                       ctxb, tokpb, histf, v, accum, maskp, mflag, out);
}

// Round 6
// 134.663 us; speedup vs baseline: 3.8505x; 3.8505x over previous
//
#include <hip/hip_runtime.h>
#include <hip/hip_bf16.h>

#define B_ 16384
#define F_ 128
#define D_ 256
#define A_ 256
#define T_ 64
#define DECAY_ 0.9f
#define SCALE2 2.885390081777927f   // 2*log2(e)
#define L2E    1.4426950408889634f  // log2(e)

typedef __attribute__((ext_vector_type(8))) __bf16 bf16x8;
typedef __attribute__((ext_vector_type(4))) float f32x4;

#if __has_builtin(__builtin_amdgcn_exp2f)
#define EXP2(x) __builtin_amdgcn_exp2f(x)
#else
#define EXP2(x) exp2f(x)
#endif
#define RCP(x) __builtin_amdgcn_rcpf(x)

__device__ __forceinline__ float tanh2(float x) {
    float e = EXP2(SCALE2 * x);
    return 1.0f - 2.0f * RCP(e + 1.0f);
}
__device__ __forceinline__ float sigmoid2(float x) {
    float e = EXP2(-L2E * x);
    return RCP(1.0f + e);
}
__device__ __forceinline__ bool get_mask(const void* mp, int mflag, int row) {
    if (mflag) return ((const unsigned char*)mp)[row] != 0;
    return ((const int*)mp)[row] != 0;
}
__device__ __forceinline__ unsigned short bfbits(float f) {
    __bf16 h = (__bf16)f;
    return __builtin_bit_cast(unsigned short, h);
}
__device__ __forceinline__ float bits2f(unsigned short u) {
    return __builtin_bit_cast(float, ((unsigned)u) << 16);
}

// ---- mask dtype probe ----
__global__ __launch_bounds__(256) void mask_probe(const unsigned int* m, int* flag) {
    __shared__ int f;
    if (threadIdx.x == 0) f = 0;
    __syncthreads();
    int any = 0;
    for (int i = threadIdx.x; i < B_ / 4; i += 256) any |= (m[i] > 1u) ? 1 : 0;
    if (any) atomicOr(&f, 1);
    __syncthreads();
    if (threadIdx.x == 0) flag[0] = f;
}

// ---- convert weights fp32 -> bf16 row-major ----
__global__ __launch_bounds__(256) void convert_w(const float* Wih, const float* Whh, const float* Wc,
                                                 __bf16* Wihb, __bf16* Whhb, __bf16* Wcb) {
    const int n1 = 768 * 128, n2 = n1 + 768 * 256, n3 = n2 + 256 * 256;
    int i = (blockIdx.x * 256 + threadIdx.x) * 4;
    if (i < n1) {
#pragma unroll
        for (int j = 0; j < 4; ++j) Wihb[i + j] = (__bf16)Wih[i + j];
    } else if (i < n2) {
        int k = i - n1;
#pragma unroll
        for (int j = 0; j < 4; ++j) Whhb[k + j] = (__bf16)Whh[k + j];
    } else if (i < n3) {
        int k = i - n2;
#pragma unroll
        for (int j = 0; j < 4; ++j) Wcb[k + j] = (__bf16)Wc[k + j];
    }
}

// ---- histb = tanh(tokens) bf16 [T,D]; tokpb = SCALE2*(hist @ Wh.T + bh) bf16 [T,A] ----
__global__ __launch_bounds__(256) void prep_kernel(const float* tokens, const float* Wh, const float* bh,
                                                   __bf16* histb, __bf16* tokpb) {
    int t = blockIdx.x, tid = threadIdx.x;
    __shared__ float hrow[D_];
    float hv = tanh2(tokens[t * D_ + tid]);
    hrow[tid] = hv;
    histb[t * D_ + tid] = (__bf16)hv;
    __syncthreads();
    float acc = bh[tid];
    const float* wr = &Wh[tid * D_];
    for (int d = 0; d < D_; d++) acc += hrow[d] * wr[d];
    tokpb[t * A_ + tid] = (__bf16)(acc * SCALE2);
}

// ---- fused GRU (MFMA, nt-split) + ctx GEMM (round-5 proven) ----
#define XS 392   // shorts/row: 384 + 8 pad
#define HS 264   // shorts/row: 256 + 8 pad
__global__ __launch_bounds__(256, 4) void gru_fused(
    const float* __restrict__ features, const float* __restrict__ h,
    const void* maskp, const int* __restrict__ mflagp,
    const __bf16* __restrict__ Wihb, const __bf16* __restrict__ Whhb, const __bf16* __restrict__ Wcb,
    const float* __restrict__ b_ih, const float* __restrict__ b_hh, const float* __restrict__ bcp,
    float* __restrict__ hout, __bf16* __restrict__ ctxb)
{
    __shared__ __bf16 Xs[32 * XS];
    __shared__ __bf16 Hn[32 * HS];
    int tid = threadIdx.x;
    int b0 = blockIdx.x * 32;
    int wv = tid >> 6, lane = tid & 63;
    int lan15 = lane & 15, kg = lane >> 4;
    int klo = kg * 8;
    int dsl = wv * 64;
    int mflag = mflagp[0];

#pragma unroll
    for (int it = 0; it < 4; ++it) {
        int idx = (it * 256 + tid) * 4;
        int r = idx >> 7, c = idx & 127;
        float4 vv = *(const float4*)&features[(size_t)(b0 + r) * F_ + c];
        ushort4 w = { bfbits(vv.x), bfbits(vv.y), bfbits(vv.z), bfbits(vv.w) };
        *reinterpret_cast<ushort4*>(&Xs[r * XS + c]) = w;
    }
#pragma unroll
    for (int it = 0; it < 8; ++it) {
        int idx = (it * 256 + tid) * 4;
        int r = idx >> 8, c = idx & 255;
        float4 vv = *(const float4*)&h[(size_t)(b0 + r) * D_ + c];
        ushort4 w = { bfbits(vv.x), bfbits(vv.y), bfbits(vv.z), bfbits(vv.w) };
        *reinterpret_cast<ushort4*>(&Xs[r * XS + 128 + c]) = w;
    }
    unsigned mbits = 0;
#pragma unroll
    for (int mt = 0; mt < 2; ++mt)
#pragma unroll
        for (int rg = 0; rg < 4; ++rg) {
            int row = mt * 16 + kg * 4 + rg;
            if (get_mask(maskp, mflag, b0 + row)) mbits |= 1u << (mt * 4 + rg);
        }
    __syncthreads();

#pragma unroll
    for (int np = 0; np < 2; ++np) {
        f32x4 ar[2][2] = {}, az[2][2] = {}, ai[2][2] = {}, ah[2][2] = {};
#pragma unroll
        for (int kb = 0; kb < 4; ++kb) {
            bf16x8 a0 = *reinterpret_cast<const bf16x8*>(&Xs[lan15 * XS + kb * 32 + klo]);
            bf16x8 a1 = *reinterpret_cast<const bf16x8*>(&Xs[(16 + lan15) * XS + kb * 32 + klo]);
#pragma unroll
            for (int ntl = 0; ntl < 2; ++ntl) {
                int nt = np * 2 + ntl;
                const __bf16* p = Wihb + (size_t)(dsl + nt * 16 + lan15) * F_ + kb * 32 + klo;
                bf16x8 br = *reinterpret_cast<const bf16x8*>(p);
                bf16x8 bz = *reinterpret_cast<const bf16x8*>(p + 256 * F_);
                bf16x8 bn = *reinterpret_cast<const bf16x8*>(p + 512 * F_);
                ar[0][ntl] = __builtin_amdgcn_mfma_f32_16x16x32_bf16(a0, br, ar[0][ntl], 0, 0, 0);
                ar[1][ntl] = __builtin_amdgcn_mfma_f32_16x16x32_bf16(a1, br, ar[1][ntl], 0, 0, 0);
                az[0][ntl] = __builtin_amdgcn_mfma_f32_16x16x32_bf16(a0, bz, az[0][ntl], 0, 0, 0);
                az[1][ntl] = __builtin_amdgcn_mfma_f32_16x16x32_bf16(a1, bz, az[1][ntl], 0, 0, 0);
                ai[0][ntl] = __builtin_amdgcn_mfma_f32_16x16x32_bf16(a0, bn, ai[0][ntl], 0, 0, 0);
                ai[1][ntl] = __builtin_amdgcn_mfma_f32_16x16x32_bf16(a1, bn, ai[1][ntl], 0, 0, 0);
            }
        }
#pragma unroll
        for (int kb = 0; kb < 8; ++kb) {
            bf16x8 a0 = *reinterpret_cast<const bf16x8*>(&Xs[lan15 * XS + 128 + kb * 32 + klo]);
            bf16x8 a1 = *reinterpret_cast<const bf16x8*>(&Xs[(16 + lan15) * XS + 128 + kb * 32 + klo]);
#pragma unroll
            for (int ntl = 0; ntl < 2; ++ntl) {
                int nt = np * 2 + ntl;
                const __bf16* p = Whhb + (size_t)(dsl + nt * 16 + lan15) * D_ + kb * 32 + klo;
                bf16x8 br = *reinterpret_cast<const bf16x8*>(p);
                bf16x8 bz = *reinterpret_cast<const bf16x8*>(p + 256 * D_);
                bf16x8 bn = *reinterpret_cast<const bf16x8*>(p + 512 * D_);
                ar[0][ntl] = __builtin_amdgcn_mfma_f32_16x16x32_bf16(a0, br, ar[0][ntl], 0, 0, 0);
                ar[1][ntl] = __builtin_amdgcn_mfma_f32_16x16x32_bf16(a1, br, ar[1][ntl], 0, 0, 0);
                az[0][ntl] = __builtin_amdgcn_mfma_f32_16x16x32_bf16(a0, bz, az[0][ntl], 0, 0, 0);
                az[1][ntl] = __builtin_amdgcn_mfma_f32_16x16x32_bf16(a1, bz, az[1][ntl], 0, 0, 0);
                ah[0][ntl] = __builtin_amdgcn_mfma_f32_16x16x32_bf16(a0, bn, ah[0][ntl], 0, 0, 0);
                ah[1][ntl] = __builtin_amdgcn_mfma_f32_16x16x32_bf16(a1, bn, ah[1][ntl], 0, 0, 0);
            }
        }
#pragma unroll
        for (int ntl = 0; ntl < 2; ++ntl) {
            int nt = np * 2 + ntl;
            int d = dsl + nt * 16 + lan15;
            float brv = b_ih[d] + b_hh[d];
            float bzv = b_ih[256 + d] + b_hh[256 + d];
            float biv = b_ih[512 + d];
            float bhv = b_hh[512 + d];
#pragma unroll
            for (int mt = 0; mt < 2; ++mt)
#pragma unroll
                for (int rg = 0; rg < 4; ++rg) {
                    int row = mt * 16 + kg * 4 + rg;
                    float hv = (float)Xs[row * XS + 128 + d];
                    float rv = sigmoid2(ar[mt][ntl][rg] + brv);
                    float zv = sigmoid2(az[mt][ntl][rg] + bzv);
                    float nv = tanh2(ai[mt][ntl][rg] + biv + rv * (ah[mt][ntl][rg] + bhv));
                    float hn = (1.0f - zv) * nv + zv * hv;
                    Hn[row * HS + d] = (__bf16)hn;
                    bool m = (mbits >> (mt * 4 + rg)) & 1u;
                    hout[(size_t)(b0 + row) * D_ + d] = m ? hn : hv;
                }
        }
    }
    __syncthreads();

    f32x4 ac[2][4] = {};
#pragma unroll
    for (int kb = 0; kb < 8; ++kb) {
        bf16x8 a0 = *reinterpret_cast<const bf16x8*>(&Hn[lan15 * HS + kb * 32 + klo]);
        bf16x8 a1 = *reinterpret_cast<const bf16x8*>(&Hn[(16 + lan15) * HS + kb * 32 + klo]);
#pragma unroll
        for (int nt = 0; nt < 4; ++nt) {
            bf16x8 b = *reinterpret_cast<const bf16x8*>(&Wcb[(size_t)(dsl + nt * 16 + lan15) * D_ + kb * 32 + klo]);
            ac[0][nt] = __builtin_amdgcn_mfma_f32_16x16x32_bf16(a0, b, ac[0][nt], 0, 0, 0);
            ac[1][nt] = __builtin_amdgcn_mfma_f32_16x16x32_bf16(a1, b, ac[1][nt], 0, 0, 0);
        }
    }
#pragma unroll
    for (int mt = 0; mt < 2; ++mt)
#pragma unroll
        for (int rg = 0; rg < 4; ++rg) {
            int row = mt * 16 + kg * 4 + rg;
#pragma unroll
            for (int nt = 0; nt < 4; ++nt) {
                int d = dsl + nt * 16 + lan15;
                ctxb[(size_t)(b0 + row) * A_ + d] = (__bf16)((ac[mt][nt][rg] + bcp[d]) * SCALE2);
            }
        }
}

// ---- attention: 256 thr, 16 rows/block, 4 rows/wave; exp-factored scores ----
// score = sum_a -2*v_a * rcp(fma(exp2(tk~), exp2(cc~), 1))
__global__ __launch_bounds__(256) void attn6(
    const __bf16* __restrict__ ctxb, const __bf16* __restrict__ tokpb,
    const __bf16* __restrict__ histb, const float* __restrict__ v,
    const float* __restrict__ accum, const void* maskp, const int* __restrict__ mflagp,
    float* __restrict__ out_emb)
{
    __shared__ __bf16 tls[T_ * A_];   // 32KB: tokp~ then hist
    __shared__ float sls[16 * T_];    // 4KB scores/weights
    int tid = threadIdx.x;
    int b0 = blockIdx.x * 16;
    int wv = tid >> 6, lane = tid & 63;
    int al = lane & 31, th = lane >> 5;
    int mflag = mflagp[0];

    for (int j = tid; j < T_ * A_ / 8; j += 256)
        ((uint4*)tls)[j] = ((const uint4*)tokpb)[j];

    int a0 = al * 8;
    float vn[8];
    {
        float4 v0 = *(const float4*)&v[a0];
        float4 v1 = *(const float4*)&v[a0 + 4];
        vn[0] = -2.f * v0.x; vn[1] = -2.f * v0.y; vn[2] = -2.f * v0.z; vn[3] = -2.f * v0.w;
        vn[4] = -2.f * v1.x; vn[5] = -2.f * v1.y; vn[6] = -2.f * v1.z; vn[7] = -2.f * v1.w;
    }
    // ec[r][j] = exp2(ctx~)
    float ec[4][8];
#pragma unroll
    for (int r = 0; r < 4; ++r) {
        bf16x8 c8 = *(const bf16x8*)&ctxb[(size_t)(b0 + wv * 4 + r) * A_ + a0];
#pragma unroll
        for (int j = 0; j < 8; ++j) ec[r][j] = EXP2((float)c8[j]);
    }
    __syncthreads();

    // scores: et shared across 4 rows
    for (int tc = 0; tc < 32; ++tc) {
        int t = tc * 2 + th;
        bf16x8 k8 = *(const bf16x8*)&tls[t * A_ + a0];
        float p0 = 0.f, p1 = 0.f, p2 = 0.f, p3 = 0.f;
#pragma unroll
        for (int j = 0; j < 8; ++j) {
            float et = EXP2((float)k8[j]);
            p0 = fmaf(vn[j], RCP(fmaf(et, ec[0][j], 1.0f)), p0);
            p1 = fmaf(vn[j], RCP(fmaf(et, ec[1][j], 1.0f)), p1);
            p2 = fmaf(vn[j], RCP(fmaf(et, ec[2][j], 1.0f)), p2);
            p3 = fmaf(vn[j], RCP(fmaf(et, ec[3][j], 1.0f)), p3);
        }
#pragma unroll
        for (int m = 1; m < 32; m <<= 1) {
            p0 += __shfl_xor(p0, m, 64);
            p1 += __shfl_xor(p1, m, 64);
            p2 += __shfl_xor(p2, m, 64);
            p3 += __shfl_xor(p3, m, 64);
        }
        if (al == 0) {
            sls[(wv * 4 + 0) * T_ + t] = p0;
            sls[(wv * 4 + 1) * T_ + t] = p1;
            sls[(wv * 4 + 2) * T_ + t] = p2;
            sls[(wv * 4 + 3) * T_ + t] = p3;
        }
    }

    // softmax per row over T (intra-wave: rows written by this wave only)
#pragma unroll
    for (int r = 0; r < 4; ++r) {
        float x = sls[(wv * 4 + r) * T_ + lane];
        float mx = x;
#pragma unroll
        for (int m = 1; m < 64; m <<= 1) mx = fmaxf(mx, __shfl_xor(mx, m, 64));
        float e = EXP2(L2E * (x - mx));
        float s = e;
#pragma unroll
        for (int m = 1; m < 64; m <<= 1) s += __shfl_xor(s, m, 64);
        sls[(wv * 4 + r) * T_ + lane] = e * RCP(s);
    }
    __syncthreads();   // all waves done reading tokp~

    // restage hist (bf16)
    for (int j = tid; j < T_ * D_ / 8; j += 256)
        ((uint4*)tls)[j] = ((const uint4*)histb)[j];
    __syncthreads();

    // emb = weights @ hist ; lane owns d-quad
    int d0 = lane * 4;
    float acc4[4][4] = {};
    for (int t = 0; t < T_; ++t) {
        ushort4 hb = *reinterpret_cast<const ushort4*>(&tls[t * D_ + d0]);
        float hf0 = bits2f(hb.x), hf1 = bits2f(hb.y), hf2 = bits2f(hb.z), hf3 = bits2f(hb.w);
#pragma unroll
        for (int r = 0; r < 4; ++r) {
            float wt = sls[(wv * 4 + r) * T_ + t];
            acc4[r][0] = fmaf(wt, hf0, acc4[r][0]);
            acc4[r][1] = fmaf(wt, hf1, acc4[r][1]);
            acc4[r][2] = fmaf(wt, hf2, acc4[r][2]);
            acc4[r][3] = fmaf(wt, hf3, acc4[r][3]);
        }
    }
#pragma unroll
    for (int r = 0; r < 4; ++r) {
        size_t row = (size_t)(b0 + wv * 4 + r);
        bool m = get_mask(maskp, mflag, (int)row);
        float4 av = *(const float4*)&accum[row * D_ + d0];
        float4 o;
        o.x = m ? fmaf(av.x, DECAY_, acc4[r][0]) : av.x;
        o.y = m ? fmaf(av.y, DECAY_, acc4[r][1]) : av.y;
        o.z = m ? fmaf(av.z, DECAY_, acc4[r][2]) : av.z;
        o.w = m ? fmaf(av.w, DECAY_, acc4[r][3]) : av.w;
        *(float4*)&out_emb[row * D_ + d0] = o;
    }
}

extern "C" void kernel_launch(void* const* d_in, const int* in_sizes, int n_in,
                              void* d_out, int out_size, void* d_ws, size_t ws_size,
                              hipStream_t stream) {
    const float* features = (const float*)d_in[0];
    const float* h        = (const float*)d_in[1];
    const float* accum    = (const float*)d_in[2];
    const void*  maskp    = d_in[3];
    const float* tokens   = (const float*)d_in[4];
    const float* Wih      = (const float*)d_in[5];
    const float* Whh      = (const float*)d_in[6];
    const float* bih      = (const float*)d_in[7];
    const float* bhh      = (const float*)d_in[8];
    const float* Wh       = (const float*)d_in[9];
    const float* bh       = (const float*)d_in[10];
    const float* Wc       = (const float*)d_in[11];
    const float* bc       = (const float*)d_in[12];
    const float* v        = (const float*)d_in[13];
    // d_in[14] = bv : softmax-invariant, unused

    float* out = (float*)d_out;  // [B*D] emb_out, then [B*D] h_out

    __bf16* Wihb  = (__bf16*)d_ws;                  // 768*128
    __bf16* Whhb  = Wihb + 768 * 128;               // 768*256
    __bf16* Wcb   = Whhb + 768 * 256;               // 256*256
    __bf16* histb = Wcb + 256 * 256;                // 64*256
    __bf16* tokpb = histb + 64 * 256;               // 64*256 (pre-scaled)
    __bf16* ctxb  = tokpb + 64 * 256;               // B*256 (pre-scaled)
    int*    mflag = (int*)(ctxb + (size_t)B_ * D_);

    hipLaunchKernelGGL(mask_probe, dim3(1), dim3(256), 0, stream,
                       (const unsigned int*)maskp, mflag);
    hipLaunchKernelGGL(convert_w, dim3(352), dim3(256), 0, stream,
                       Wih, Whh, Wc, Wihb, Whhb, Wcb);
    hipLaunchKernelGGL(prep_kernel, dim3(64), dim3(256), 0, stream,
                       tokens, Wh, bh, histb, tokpb);
    hipLaunchKernelGGL(gru_fused, dim3(B_ / 32), dim3(256), 0, stream,
                       features, h, maskp, mflag, Wihb, Whhb, Wcb, bih, bhh, bc,
                       out + (size_t)B_ * D_, ctxb);
    hipLaunchKernelGGL(attn6, dim3(B_ / 16), dim3(256), 0, stream,
                       ctxb, tokpb, histb, v, accum, maskp, mflag, out);
}

// Round 7
// 129.679 us; speedup vs baseline: 3.9984x; 1.0384x over previous
//
#include <hip/hip_runtime.h>
#include <hip/hip_bf16.h>

#define B_ 16384
#define F_ 128
#define D_ 256
#define A_ 256
#define T_ 64
#define DECAY_ 0.9f
#define SCALE2 2.885390081777927f   // 2*log2(e)
#define L2E    1.4426950408889634f  // log2(e)

typedef __attribute__((ext_vector_type(8))) __bf16 bf16x8;
typedef __attribute__((ext_vector_type(4))) float f32x4;

#if __has_builtin(__builtin_amdgcn_exp2f)
#define EXP2(x) __builtin_amdgcn_exp2f(x)
#else
#define EXP2(x) exp2f(x)
#endif
#define RCP(x) __builtin_amdgcn_rcpf(x)

__device__ __forceinline__ float tanh2(float x) {
    float e = EXP2(SCALE2 * x);
    return 1.0f - 2.0f * RCP(e + 1.0f);
}
__device__ __forceinline__ float sigmoid2(float x) {
    float e = EXP2(-L2E * x);
    return RCP(1.0f + e);
}
__device__ __forceinline__ bool get_mask(const void* mp, int mflag, int row) {
    if (mflag) return ((const unsigned char*)mp)[row] != 0;
    return ((const int*)mp)[row] != 0;
}
__device__ __forceinline__ unsigned short bfbits(float f) {
    __bf16 h = (__bf16)f;
    return __builtin_bit_cast(unsigned short, h);
}
__device__ __forceinline__ float bits2f(unsigned short u) {
    return __builtin_bit_cast(float, ((unsigned)u) << 16);
}

// ---- mask dtype probe ----
__global__ __launch_bounds__(256) void mask_probe(const unsigned int* m, int* flag) {
    __shared__ int f;
    if (threadIdx.x == 0) f = 0;
    __syncthreads();
    int any = 0;
    for (int i = threadIdx.x; i < B_ / 4; i += 256) any |= (m[i] > 1u) ? 1 : 0;
    if (any) atomicOr(&f, 1);
    __syncthreads();
    if (threadIdx.x == 0) flag[0] = f;
}

// ---- convert weights fp32 -> bf16 row-major ----
__global__ __launch_bounds__(256) void convert_w(const float* Wih, const float* Whh, const float* Wc,
                                                 __bf16* Wihb, __bf16* Whhb, __bf16* Wcb) {
    const int n1 = 768 * 128, n2 = n1 + 768 * 256, n3 = n2 + 256 * 256;
    int i = (blockIdx.x * 256 + threadIdx.x) * 4;
    if (i < n1) {
#pragma unroll
        for (int j = 0; j < 4; ++j) Wihb[i + j] = (__bf16)Wih[i + j];
    } else if (i < n2) {
        int k = i - n1;
#pragma unroll
        for (int j = 0; j < 4; ++j) Whhb[k + j] = (__bf16)Whh[k + j];
    } else if (i < n3) {
        int k = i - n2;
#pragma unroll
        for (int j = 0; j < 4; ++j) Wcb[k + j] = (__bf16)Wc[k + j];
    }
}

// ---- histb = tanh(tokens) bf16 [T,D]; tokpb = SCALE2*(hist @ Wh.T + bh) bf16 [T,A] ----
__global__ __launch_bounds__(256) void prep_kernel(const float* tokens, const float* Wh, const float* bh,
                                                   __bf16* histb, __bf16* tokpb) {
    int t = blockIdx.x, tid = threadIdx.x;
    __shared__ float hrow[D_];
    float hv = tanh2(tokens[t * D_ + tid]);
    hrow[tid] = hv;
    histb[t * D_ + tid] = (__bf16)hv;
    __syncthreads();
    float acc = bh[tid];
    const float* wr = &Wh[tid * D_];
    for (int d = 0; d < D_; d++) acc += hrow[d] * wr[d];
    tokpb[t * A_ + tid] = (__bf16)(acc * SCALE2);
}

// ---- fused GRU (MFMA, monolithic — round-4-proven) + ctx GEMM; ctx out pre-scaled bf16 ----
#define XS 392   // shorts/row: 384 + 8 pad
#define HS 264   // shorts/row: 256 + 8 pad
__global__ __launch_bounds__(256, 2) void gru_fused(
    const float* __restrict__ features, const float* __restrict__ h,
    const void* maskp, const int* __restrict__ mflagp,
    const __bf16* __restrict__ Wihb, const __bf16* __restrict__ Whhb, const __bf16* __restrict__ Wcb,
    const float* __restrict__ b_ih, const float* __restrict__ b_hh, const float* __restrict__ bcp,
    float* __restrict__ hout, __bf16* __restrict__ ctxb)
{
    __shared__ __bf16 Xs[32 * XS];
    __shared__ __bf16 Hn[32 * HS];
    int tid = threadIdx.x;
    int b0 = blockIdx.x * 32;
    int wv = tid >> 6, lane = tid & 63;
    int lan15 = lane & 15, kg = lane >> 4;
    int klo = kg * 8;
    int dsl = wv * 64;
    int mflag = mflagp[0];

#pragma unroll
    for (int it = 0; it < 4; ++it) {
        int idx = (it * 256 + tid) * 4;
        int r = idx >> 7, c = idx & 127;
        float4 vv = *(const float4*)&features[(size_t)(b0 + r) * F_ + c];
        ushort4 w = { bfbits(vv.x), bfbits(vv.y), bfbits(vv.z), bfbits(vv.w) };
        *reinterpret_cast<ushort4*>(&Xs[r * XS + c]) = w;
    }
#pragma unroll
    for (int it = 0; it < 8; ++it) {
        int idx = (it * 256 + tid) * 4;
        int r = idx >> 8, c = idx & 255;
        float4 vv = *(const float4*)&h[(size_t)(b0 + r) * D_ + c];
        ushort4 w = { bfbits(vv.x), bfbits(vv.y), bfbits(vv.z), bfbits(vv.w) };
        *reinterpret_cast<ushort4*>(&Xs[r * XS + 128 + c]) = w;
    }
    float brv[4], bzv[4], biv[4], bhv[4], bcv[4];
#pragma unroll
    for (int nt = 0; nt < 4; ++nt) {
        int d = dsl + nt * 16 + lan15;
        brv[nt] = b_ih[d] + b_hh[d];
        bzv[nt] = b_ih[256 + d] + b_hh[256 + d];
        biv[nt] = b_ih[512 + d];
        bhv[nt] = b_hh[512 + d];
        bcv[nt] = bcp[d];
    }
    __syncthreads();

    f32x4 ar[2][4] = {}, az[2][4] = {}, ai[2][4] = {}, ah[2][4] = {};

#pragma unroll
    for (int kb = 0; kb < 4; ++kb) {
        bf16x8 a0 = *reinterpret_cast<const bf16x8*>(&Xs[lan15 * XS + kb * 32 + klo]);
        bf16x8 a1 = *reinterpret_cast<const bf16x8*>(&Xs[(16 + lan15) * XS + kb * 32 + klo]);
#pragma unroll
        for (int nt = 0; nt < 4; ++nt) {
            const __bf16* p = Wihb + (size_t)(dsl + nt * 16 + lan15) * F_ + kb * 32 + klo;
            bf16x8 br = *reinterpret_cast<const bf16x8*>(p);
            bf16x8 bz = *reinterpret_cast<const bf16x8*>(p + 256 * F_);
            bf16x8 bn = *reinterpret_cast<const bf16x8*>(p + 512 * F_);
            ar[0][nt] = __builtin_amdgcn_mfma_f32_16x16x32_bf16(a0, br, ar[0][nt], 0, 0, 0);
            ar[1][nt] = __builtin_amdgcn_mfma_f32_16x16x32_bf16(a1, br, ar[1][nt], 0, 0, 0);
            az[0][nt] = __builtin_amdgcn_mfma_f32_16x16x32_bf16(a0, bz, az[0][nt], 0, 0, 0);
            az[1][nt] = __builtin_amdgcn_mfma_f32_16x16x32_bf16(a1, bz, az[1][nt], 0, 0, 0);
            ai[0][nt] = __builtin_amdgcn_mfma_f32_16x16x32_bf16(a0, bn, ai[0][nt], 0, 0, 0);
            ai[1][nt] = __builtin_amdgcn_mfma_f32_16x16x32_bf16(a1, bn, ai[1][nt], 0, 0, 0);
        }
    }
#pragma unroll
    for (int kb = 0; kb < 8; ++kb) {
        bf16x8 a0 = *reinterpret_cast<const bf16x8*>(&Xs[lan15 * XS + 128 + kb * 32 + klo]);
        bf16x8 a1 = *reinterpret_cast<const bf16x8*>(&Xs[(16 + lan15) * XS + 128 + kb * 32 + klo]);
#pragma unroll
        for (int nt = 0; nt < 4; ++nt) {
            const __bf16* p = Whhb + (size_t)(dsl + nt * 16 + lan15) * D_ + kb * 32 + klo;
            bf16x8 br = *reinterpret_cast<const bf16x8*>(p);
            bf16x8 bz = *reinterpret_cast<const bf16x8*>(p + 256 * D_);
            bf16x8 bn = *reinterpret_cast<const bf16x8*>(p + 512 * D_);
            ar[0][nt] = __builtin_amdgcn_mfma_f32_16x16x32_bf16(a0, br, ar[0][nt], 0, 0, 0);
            ar[1][nt] = __builtin_amdgcn_mfma_f32_16x16x32_bf16(a1, br, ar[1][nt], 0, 0, 0);
            az[0][nt] = __builtin_amdgcn_mfma_f32_16x16x32_bf16(a0, bz, az[0][nt], 0, 0, 0);
            az[1][nt] = __builtin_amdgcn_mfma_f32_16x16x32_bf16(a1, bz, az[1][nt], 0, 0, 0);
            ah[0][nt] = __builtin_amdgcn_mfma_f32_16x16x32_bf16(a0, bn, ah[0][nt], 0, 0, 0);
            ah[1][nt] = __builtin_amdgcn_mfma_f32_16x16x32_bf16(a1, bn, ah[1][nt], 0, 0, 0);
        }
    }

#pragma unroll
    for (int mt = 0; mt < 2; ++mt) {
#pragma unroll
        for (int rg = 0; rg < 4; ++rg) {
            int row = mt * 16 + kg * 4 + rg;
            int grow = b0 + row;
            bool m = get_mask(maskp, mflag, grow);
#pragma unroll
            for (int nt = 0; nt < 4; ++nt) {
                int d = dsl + nt * 16 + lan15;
                float hv = (float)Xs[row * XS + 128 + d];
                float rv = sigmoid2(ar[mt][nt][rg] + brv[nt]);
                float zv = sigmoid2(az[mt][nt][rg] + bzv[nt]);
                float nv = tanh2(ai[mt][nt][rg] + biv[nt] + rv * (ah[mt][nt][rg] + bhv[nt]));
                float hn = (1.0f - zv) * nv + zv * hv;
                Hn[row * HS + d] = (__bf16)hn;
                hout[(size_t)grow * D_ + d] = m ? hn : hv;
            }
        }
    }
    __syncthreads();

    f32x4 ac[2][4] = {};
#pragma unroll
    for (int kb = 0; kb < 8; ++kb) {
        bf16x8 a0 = *reinterpret_cast<const bf16x8*>(&Hn[lan15 * HS + kb * 32 + klo]);
        bf16x8 a1 = *reinterpret_cast<const bf16x8*>(&Hn[(16 + lan15) * HS + kb * 32 + klo]);
#pragma unroll
        for (int nt = 0; nt < 4; ++nt) {
            bf16x8 b = *reinterpret_cast<const bf16x8*>(&Wcb[(size_t)(dsl + nt * 16 + lan15) * D_ + kb * 32 + klo]);
            ac[0][nt] = __builtin_amdgcn_mfma_f32_16x16x32_bf16(a0, b, ac[0][nt], 0, 0, 0);
            ac[1][nt] = __builtin_amdgcn_mfma_f32_16x16x32_bf16(a1, b, ac[1][nt], 0, 0, 0);
        }
    }
#pragma unroll
    for (int mt = 0; mt < 2; ++mt) {
#pragma unroll
        for (int rg = 0; rg < 4; ++rg) {
            int row = mt * 16 + kg * 4 + rg;
#pragma unroll
            for (int nt = 0; nt < 4; ++nt) {
                int d = dsl + nt * 16 + lan15;
                ctxb[(size_t)(b0 + row) * A_ + d] = (__bf16)((ac[mt][nt][rg] + bcv[nt]) * SCALE2);
            }
        }
    }
}

// ---- attention: 256 thr, 16 rows/block, 4 rows/wave; exp-factored scores (round-6 proven) ----
// score = sum_a -2*v_a * rcp(fma(exp2(tk~), exp2(cc~), 1))
__global__ __launch_bounds__(256) void attn6(
    const __bf16* __restrict__ ctxb, const __bf16* __restrict__ tokpb,
    const __bf16* __restrict__ histb, const float* __restrict__ v,
    const float* __restrict__ accum, const void* maskp, const int* __restrict__ mflagp,
    float* __restrict__ out_emb)
{
    __shared__ __bf16 tls[T_ * A_];   // 32KB: tokp~ then hist
    __shared__ float sls[16 * T_];    // 4KB scores/weights
    int tid = threadIdx.x;
    int b0 = blockIdx.x * 16;
    int wv = tid >> 6, lane = tid & 63;
    int al = lane & 31, th = lane >> 5;
    int mflag = mflagp[0];

    for (int j = tid; j < T_ * A_ / 8; j += 256)
        ((uint4*)tls)[j] = ((const uint4*)tokpb)[j];

    int a0 = al * 8;
    float vn[8];
    {
        float4 v0 = *(const float4*)&v[a0];
        float4 v1 = *(const float4*)&v[a0 + 4];
        vn[0] = -2.f * v0.x; vn[1] = -2.f * v0.y; vn[2] = -2.f * v0.z; vn[3] = -2.f * v0.w;
        vn[4] = -2.f * v1.x; vn[5] = -2.f * v1.y; vn[6] = -2.f * v1.z; vn[7] = -2.f * v1.w;
    }
    // ec[r][j] = exp2(ctx~)
    float ec[4][8];
#pragma unroll
    for (int r = 0; r < 4; ++r) {
        bf16x8 c8 = *(const bf16x8*)&ctxb[(size_t)(b0 + wv * 4 + r) * A_ + a0];
#pragma unroll
        for (int j = 0; j < 8; ++j) ec[r][j] = EXP2((float)c8[j]);
    }
    __syncthreads();

    // scores: et shared across 4 rows
    for (int tc = 0; tc < 32; ++tc) {
        int t = tc * 2 + th;
        bf16x8 k8 = *(const bf16x8*)&tls[t * A_ + a0];
        float p0 = 0.f, p1 = 0.f, p2 = 0.f, p3 = 0.f;
#pragma unroll
        for (int j = 0; j < 8; ++j) {
            float et = EXP2((float)k8[j]);
            p0 = fmaf(vn[j], RCP(fmaf(et, ec[0][j], 1.0f)), p0);
            p1 = fmaf(vn[j], RCP(fmaf(et, ec[1][j], 1.0f)), p1);
            p2 = fmaf(vn[j], RCP(fmaf(et, ec[2][j], 1.0f)), p2);
            p3 = fmaf(vn[j], RCP(fmaf(et, ec[3][j], 1.0f)), p3);
        }
#pragma unroll
        for (int m = 1; m < 32; m <<= 1) {
            p0 += __shfl_xor(p0, m, 64);
            p1 += __shfl_xor(p1, m, 64);
            p2 += __shfl_xor(p2, m, 64);
            p3 += __shfl_xor(p3, m, 64);
        }
        if (al == 0) {
            sls[(wv * 4 + 0) * T_ + t] = p0;
            sls[(wv * 4 + 1) * T_ + t] = p1;
            sls[(wv * 4 + 2) * T_ + t] = p2;
            sls[(wv * 4 + 3) * T_ + t] = p3;
        }
    }

    // softmax per row over T (intra-wave: rows written by this wave only)
#pragma unroll
    for (int r = 0; r < 4; ++r) {
        float x = sls[(wv * 4 + r) * T_ + lane];
        float mx = x;
#pragma unroll
        for (int m = 1; m < 64; m <<= 1) mx = fmaxf(mx, __shfl_xor(mx, m, 64));
        float e = EXP2(L2E * (x - mx));
        float s = e;
#pragma unroll
        for (int m = 1; m < 64; m <<= 1) s += __shfl_xor(s, m, 64);
        sls[(wv * 4 + r) * T_ + lane] = e * RCP(s);
    }
    __syncthreads();   // all waves done reading tokp~

    // restage hist (bf16)
    for (int j = tid; j < T_ * D_ / 8; j += 256)
        ((uint4*)tls)[j] = ((const uint4*)histb)[j];
    __syncthreads();

    // emb = weights @ hist ; lane owns d-quad
    int d0 = lane * 4;
    float acc4[4][4] = {};
    for (int t = 0; t < T_; ++t) {
        ushort4 hb = *reinterpret_cast<const ushort4*>(&tls[t * D_ + d0]);
        float hf0 = bits2f(hb.x), hf1 = bits2f(hb.y), hf2 = bits2f(hb.z), hf3 = bits2f(hb.w);
#pragma unroll
        for (int r = 0; r < 4; ++r) {
            float wt = sls[(wv * 4 + r) * T_ + t];
            acc4[r][0] = fmaf(wt, hf0, acc4[r][0]);
            acc4[r][1] = fmaf(wt, hf1, acc4[r][1]);
            acc4[r][2] = fmaf(wt, hf2, acc4[r][2]);
            acc4[r][3] = fmaf(wt, hf3, acc4[r][3]);
        }
    }
#pragma unroll
    for (int r = 0; r < 4; ++r) {
        size_t row = (size_t)(b0 + wv * 4 + r);
        bool m = get_mask(maskp, mflag, (int)row);
        float4 av = *(const float4*)&accum[row * D_ + d0];
        float4 o;
        o.x = m ? fmaf(av.x, DECAY_, acc4[r][0]) : av.x;
        o.y = m ? fmaf(av.y, DECAY_, acc4[r][1]) : av.y;
        o.z = m ? fmaf(av.z, DECAY_, acc4[r][2]) : av.z;
        o.w = m ? fmaf(av.w, DECAY_, acc4[r][3]) : av.w;
        *(float4*)&out_emb[row * D_ + d0] = o;
    }
}

extern "C" void kernel_launch(void* const* d_in, const int* in_sizes, int n_in,
                              void* d_out, int out_size, void* d_ws, size_t ws_size,
                              hipStream_t stream) {
    const float* features = (const float*)d_in[0];
    const float* h        = (const float*)d_in[1];
    const float* accum    = (const float*)d_in[2];
    const void*  maskp    = d_in[3];
    const float* tokens   = (const float*)d_in[4];
    const float* Wih      = (const float*)d_in[5];
    const float* Whh      = (const float*)d_in[6];
    const float* bih      = (const float*)d_in[7];
    const float* bhh      = (const float*)d_in[8];
    const float* Wh       = (const float*)d_in[9];
    const float* bh       = (const float*)d_in[10];
    const float* Wc       = (const float*)d_in[11];
    const float* bc       = (const float*)d_in[12];
    const float* v        = (const float*)d_in[13];
    // d_in[14] = bv : softmax-invariant, unused

    float* out = (float*)d_out;  // [B*D] emb_out, then [B*D] h_out

    __bf16* Wihb  = (__bf16*)d_ws;                  // 768*128
    __bf16* Whhb  = Wihb + 768 * 128;               // 768*256
    __bf16* Wcb   = Whhb + 768 * 256;               // 256*256
    __bf16* histb = Wcb + 256 * 256;                // 64*256
    __bf16* tokpb = histb + 64 * 256;               // 64*256 (pre-scaled)
    __bf16* ctxb  = tokpb + 64 * 256;               // B*256 (pre-scaled)
    int*    mflag = (int*)(ctxb + (size_t)B_ * D_);

    hipLaunchKernelGGL(mask_probe, dim3(1), dim3(256), 0, stream,
                       (const unsigned int*)maskp, mflag);
    hipLaunchKernelGGL(convert_w, dim3(352), dim3(256), 0, stream,
                       Wih, Whh, Wc, Wihb, Whhb, Wcb);
    hipLaunchKernelGGL(prep_kernel, dim3(64), dim3(256), 0, stream,
                       tokens, Wh, bh, histb, tokpb);
    hipLaunchKernelGGL(gru_fused, dim3(B_ / 32), dim3(256), 0, stream,
                       features, h, maskp, mflag, Wihb, Whhb, Wcb, bih, bhh, bc,
                       out + (size_t)B_ * D_, ctxb);
    hipLaunchKernelGGL(attn6, dim3(B_ / 16), dim3(256), 0, stream,
                       ctxb, tokpb, histb, v, accum, maskp, mflag, out);
}

// Round 8
// 123.247 us; speedup vs baseline: 4.2071x; 1.0522x over previous
//
#include <hip/hip_runtime.h>
#include <hip/hip_bf16.h>

#define B_ 16384
#define F_ 128
#define D_ 256
#define A_ 256
#define T_ 64
#define DECAY_ 0.9f
#define SCALE2 2.885390081777927f   // 2*log2(e)
#define L2E    1.4426950408889634f  // log2(e)

typedef __attribute__((ext_vector_type(8))) __bf16 bf16x8;
typedef __attribute__((ext_vector_type(4))) float f32x4;

#if __has_builtin(__builtin_amdgcn_exp2f)
#define EXP2(x) __builtin_amdgcn_exp2f(x)
#else
#define EXP2(x) exp2f(x)
#endif
#define RCP(x) __builtin_amdgcn_rcpf(x)

__device__ __forceinline__ float tanh2(float x) {
    float e = EXP2(SCALE2 * x);
    return 1.0f - 2.0f * RCP(e + 1.0f);
}
__device__ __forceinline__ float sigmoid2(float x) {
    float e = EXP2(-L2E * x);
    return RCP(1.0f + e);
}
__device__ __forceinline__ bool get_mask(const void* mp, int mflag, int row) {
    if (mflag) return ((const unsigned char*)mp)[row] != 0;
    return ((const int*)mp)[row] != 0;
}
__device__ __forceinline__ unsigned short bfbits(float f) {
    __bf16 h = (__bf16)f;
    return __builtin_bit_cast(unsigned short, h);
}
__device__ __forceinline__ float bits2f(unsigned short u) {
    return __builtin_bit_cast(float, ((unsigned)u) << 16);
}

// ---- mask dtype probe ----
__global__ __launch_bounds__(256) void mask_probe(const unsigned int* m, int* flag) {
    __shared__ int f;
    if (threadIdx.x == 0) f = 0;
    __syncthreads();
    int any = 0;
    for (int i = threadIdx.x; i < B_ / 4; i += 256) any |= (m[i] > 1u) ? 1 : 0;
    if (any) atomicOr(&f, 1);
    __syncthreads();
    if (threadIdx.x == 0) flag[0] = f;
}

// ---- convert weights fp32 -> bf16 row-major ----
__global__ __launch_bounds__(256) void convert_w(const float* Wih, const float* Whh, const float* Wc,
                                                 __bf16* Wihb, __bf16* Whhb, __bf16* Wcb) {
    const int n1 = 768 * 128, n2 = n1 + 768 * 256, n3 = n2 + 256 * 256;
    int i = (blockIdx.x * 256 + threadIdx.x) * 4;
    if (i < n1) {
#pragma unroll
        for (int j = 0; j < 4; ++j) Wihb[i + j] = (__bf16)Wih[i + j];
    } else if (i < n2) {
        int k = i - n1;
#pragma unroll
        for (int j = 0; j < 4; ++j) Whhb[k + j] = (__bf16)Whh[k + j];
    } else if (i < n3) {
        int k = i - n2;
#pragma unroll
        for (int j = 0; j < 4; ++j) Wcb[k + j] = (__bf16)Wc[k + j];
    }
}

// ---- histf = tanh(tokens) f32 [T,D]; etp = bf16(exp2(SCALE2*(hist@Wh.T+bh))) in packed layout ----
// etp layout: element (a,t) at (a>>2)*256 + t*4 + (a&3)   [quad-of-a packed per t]
__global__ __launch_bounds__(256) void prep_kernel(const float* tokens, const float* Wh, const float* bh,
                                                   float* histf, __bf16* etp) {
    int t = blockIdx.x, tid = threadIdx.x;   // tid = a
    __shared__ float hrow[D_];
    float hv = tanh2(tokens[t * D_ + tid]);
    hrow[tid] = hv;
    histf[t * D_ + tid] = hv;
    __syncthreads();
    float acc = bh[tid];
    const float* wr = &Wh[tid * D_];
    for (int d = 0; d < D_; d++) acc += hrow[d] * wr[d];
    etp[(tid >> 2) * 256 + t * 4 + (tid & 3)] = (__bf16)EXP2(acc * SCALE2);
}

// ---- fused GRU (MFMA, monolithic — proven) + ctx GEMM; epilogue writes ec = bf16(exp2(ctx~)) ----
#define XS 392   // shorts/row: 384 + 8 pad
#define HS 264   // shorts/row: 256 + 8 pad
__global__ __launch_bounds__(256, 2) void gru_fused(
    const float* __restrict__ features, const float* __restrict__ h,
    const void* maskp, const int* __restrict__ mflagp,
    const __bf16* __restrict__ Wihb, const __bf16* __restrict__ Whhb, const __bf16* __restrict__ Wcb,
    const float* __restrict__ b_ih, const float* __restrict__ b_hh, const float* __restrict__ bcp,
    float* __restrict__ hout, __bf16* __restrict__ ecb)
{
    __shared__ __bf16 Xs[32 * XS];
    __shared__ __bf16 Hn[32 * HS];
    int tid = threadIdx.x;
    int b0 = blockIdx.x * 32;
    int wv = tid >> 6, lane = tid & 63;
    int lan15 = lane & 15, kg = lane >> 4;
    int klo = kg * 8;
    int dsl = wv * 64;
    int mflag = mflagp[0];

#pragma unroll
    for (int it = 0; it < 4; ++it) {
        int idx = (it * 256 + tid) * 4;
        int r = idx >> 7, c = idx & 127;
        float4 vv = *(const float4*)&features[(size_t)(b0 + r) * F_ + c];
        ushort4 w = { bfbits(vv.x), bfbits(vv.y), bfbits(vv.z), bfbits(vv.w) };
        *reinterpret_cast<ushort4*>(&Xs[r * XS + c]) = w;
    }
#pragma unroll
    for (int it = 0; it < 8; ++it) {
        int idx = (it * 256 + tid) * 4;
        int r = idx >> 8, c = idx & 255;
        float4 vv = *(const float4*)&h[(size_t)(b0 + r) * D_ + c];
        ushort4 w = { bfbits(vv.x), bfbits(vv.y), bfbits(vv.z), bfbits(vv.w) };
        *reinterpret_cast<ushort4*>(&Xs[r * XS + 128 + c]) = w;
    }
    float brv[4], bzv[4], biv[4], bhv[4], bcv[4];
#pragma unroll
    for (int nt = 0; nt < 4; ++nt) {
        int d = dsl + nt * 16 + lan15;
        brv[nt] = b_ih[d] + b_hh[d];
        bzv[nt] = b_ih[256 + d] + b_hh[256 + d];
        biv[nt] = b_ih[512 + d];
        bhv[nt] = b_hh[512 + d];
        bcv[nt] = bcp[d];
    }
    __syncthreads();

    f32x4 ar[2][4] = {}, az[2][4] = {}, ai[2][4] = {}, ah[2][4] = {};

#pragma unroll
    for (int kb = 0; kb < 4; ++kb) {
        bf16x8 a0 = *reinterpret_cast<const bf16x8*>(&Xs[lan15 * XS + kb * 32 + klo]);
        bf16x8 a1 = *reinterpret_cast<const bf16x8*>(&Xs[(16 + lan15) * XS + kb * 32 + klo]);
#pragma unroll
        for (int nt = 0; nt < 4; ++nt) {
            const __bf16* p = Wihb + (size_t)(dsl + nt * 16 + lan15) * F_ + kb * 32 + klo;
            bf16x8 br = *reinterpret_cast<const bf16x8*>(p);
            bf16x8 bz = *reinterpret_cast<const bf16x8*>(p + 256 * F_);
            bf16x8 bn = *reinterpret_cast<const bf16x8*>(p + 512 * F_);
            ar[0][nt] = __builtin_amdgcn_mfma_f32_16x16x32_bf16(a0, br, ar[0][nt], 0, 0, 0);
            ar[1][nt] = __builtin_amdgcn_mfma_f32_16x16x32_bf16(a1, br, ar[1][nt], 0, 0, 0);
            az[0][nt] = __builtin_amdgcn_mfma_f32_16x16x32_bf16(a0, bz, az[0][nt], 0, 0, 0);
            az[1][nt] = __builtin_amdgcn_mfma_f32_16x16x32_bf16(a1, bz, az[1][nt], 0, 0, 0);
            ai[0][nt] = __builtin_amdgcn_mfma_f32_16x16x32_bf16(a0, bn, ai[0][nt], 0, 0, 0);
            ai[1][nt] = __builtin_amdgcn_mfma_f32_16x16x32_bf16(a1, bn, ai[1][nt], 0, 0, 0);
        }
    }
#pragma unroll
    for (int kb = 0; kb < 8; ++kb) {
        bf16x8 a0 = *reinterpret_cast<const bf16x8*>(&Xs[lan15 * XS + 128 + kb * 32 + klo]);
        bf16x8 a1 = *reinterpret_cast<const bf16x8*>(&Xs[(16 + lan15) * XS + 128 + kb * 32 + klo]);
#pragma unroll
        for (int nt = 0; nt < 4; ++nt) {
            const __bf16* p = Whhb + (size_t)(dsl + nt * 16 + lan15) * D_ + kb * 32 + klo;
            bf16x8 br = *reinterpret_cast<const bf16x8*>(p);
            bf16x8 bz = *reinterpret_cast<const bf16x8*>(p + 256 * D_);
            bf16x8 bn = *reinterpret_cast<const bf16x8*>(p + 512 * D_);
            ar[0][nt] = __builtin_amdgcn_mfma_f32_16x16x32_bf16(a0, br, ar[0][nt], 0, 0, 0);
            ar[1][nt] = __builtin_amdgcn_mfma_f32_16x16x32_bf16(a1, br, ar[1][nt], 0, 0, 0);
            az[0][nt] = __builtin_amdgcn_mfma_f32_16x16x32_bf16(a0, bz, az[0][nt], 0, 0, 0);
            az[1][nt] = __builtin_amdgcn_mfma_f32_16x16x32_bf16(a1, bz, az[1][nt], 0, 0, 0);
            ah[0][nt] = __builtin_amdgcn_mfma_f32_16x16x32_bf16(a0, bn, ah[0][nt], 0, 0, 0);
            ah[1][nt] = __builtin_amdgcn_mfma_f32_16x16x32_bf16(a1, bn, ah[1][nt], 0, 0, 0);
        }
    }

#pragma unroll
    for (int mt = 0; mt < 2; ++mt) {
#pragma unroll
        for (int rg = 0; rg < 4; ++rg) {
            int row = mt * 16 + kg * 4 + rg;
            int grow = b0 + row;
            bool m = get_mask(maskp, mflag, grow);
#pragma unroll
            for (int nt = 0; nt < 4; ++nt) {
                int d = dsl + nt * 16 + lan15;
                float hv = (float)Xs[row * XS + 128 + d];
                float rv = sigmoid2(ar[mt][nt][rg] + brv[nt]);
                float zv = sigmoid2(az[mt][nt][rg] + bzv[nt]);
                float nv = tanh2(ai[mt][nt][rg] + biv[nt] + rv * (ah[mt][nt][rg] + bhv[nt]));
                float hn = (1.0f - zv) * nv + zv * hv;
                Hn[row * HS + d] = (__bf16)hn;
                hout[(size_t)grow * D_ + d] = m ? hn : hv;
            }
        }
    }
    __syncthreads();

    f32x4 ac[2][4] = {};
#pragma unroll
    for (int kb = 0; kb < 8; ++kb) {
        bf16x8 a0 = *reinterpret_cast<const bf16x8*>(&Hn[lan15 * HS + kb * 32 + klo]);
        bf16x8 a1 = *reinterpret_cast<const bf16x8*>(&Hn[(16 + lan15) * HS + kb * 32 + klo]);
#pragma unroll
        for (int nt = 0; nt < 4; ++nt) {
            bf16x8 b = *reinterpret_cast<const bf16x8*>(&Wcb[(size_t)(dsl + nt * 16 + lan15) * D_ + kb * 32 + klo]);
            ac[0][nt] = __builtin_amdgcn_mfma_f32_16x16x32_bf16(a0, b, ac[0][nt], 0, 0, 0);
            ac[1][nt] = __builtin_amdgcn_mfma_f32_16x16x32_bf16(a1, b, ac[1][nt], 0, 0, 0);
        }
    }
#pragma unroll
    for (int mt = 0; mt < 2; ++mt) {
#pragma unroll
        for (int rg = 0; rg < 4; ++rg) {
            int row = mt * 16 + kg * 4 + rg;
#pragma unroll
            for (int nt = 0; nt < 4; ++nt) {
                int d = dsl + nt * 16 + lan15;
                ecb[(size_t)(b0 + row) * A_ + d] = (__bf16)EXP2((ac[mt][nt][rg] + bcv[nt]) * SCALE2);
            }
        }
    }
}

// ---- attention v7: t-per-lane, precomputed et/ec, LDS = weights only (2KB) ----
// sigma~ = rcp(fma(et, ec, 1)); score = -2 * sum_a v_a * sigma~   (+const dropped)
__global__ __launch_bounds__(256) void attn7(
    const __bf16* __restrict__ ecb, const unsigned short* __restrict__ etp,
    const float* __restrict__ histf, const float* __restrict__ v,
    const float* __restrict__ accum, const void* maskp, const int* __restrict__ mflagp,
    float* __restrict__ out_emb)
{
    __shared__ float sls[8 * T_];    // 2KB softmax weights
    int tid = threadIdx.x;
    int b0 = blockIdx.x * 8;
    int wv = tid >> 6, lane = tid & 63;   // lane = t
    int mflag = mflagp[0];

    const __bf16* ec0p = ecb + (size_t)(b0 + wv * 2) * A_;
    const __bf16* ec1p = ec0p + A_;

    float p0 = 0.f, p1 = 0.f;
#pragma unroll 4
    for (int ch = 0; ch < 32; ++ch) {
        int a0 = ch * 8;
        const unsigned short* ep = etp + (a0 >> 2) * 256 + lane * 4;
        uint2 q0 = *(const uint2*)ep;            // et for a0..a0+3 at this lane's t
        uint2 q1 = *(const uint2*)(ep + 256);    // a0+4..a0+7
        bf16x8 c0 = *(const bf16x8*)&ec0p[a0];   // wave-uniform broadcast
        bf16x8 c1 = *(const bf16x8*)&ec1p[a0];
        float4 vA = *(const float4*)&v[a0];
        float4 vB = *(const float4*)&v[a0 + 4];
        float et[8];
        et[0] = __builtin_bit_cast(float, q0.x << 16);
        et[1] = __builtin_bit_cast(float, q0.x & 0xffff0000u);
        et[2] = __builtin_bit_cast(float, q0.y << 16);
        et[3] = __builtin_bit_cast(float, q0.y & 0xffff0000u);
        et[4] = __builtin_bit_cast(float, q1.x << 16);
        et[5] = __builtin_bit_cast(float, q1.x & 0xffff0000u);
        et[6] = __builtin_bit_cast(float, q1.y << 16);
        et[7] = __builtin_bit_cast(float, q1.y & 0xffff0000u);
#pragma unroll
        for (int j = 0; j < 8; ++j) {
            float vj = (j < 4) ? ((const float*)&vA)[j] : ((const float*)&vB)[j - 4];
            p0 = fmaf(vj, RCP(fmaf(et[j], (float)c0[j], 1.0f)), p0);
            p1 = fmaf(vj, RCP(fmaf(et[j], (float)c1[j], 1.0f)), p1);
        }
    }

    // softmax across lanes (lane = t), rows owned by this wave
    float x0 = -2.0f * p0, x1 = -2.0f * p1;
    float mx0 = x0, mx1 = x1;
#pragma unroll
    for (int m = 1; m < 64; m <<= 1) {
        mx0 = fmaxf(mx0, __shfl_xor(mx0, m, 64));
        mx1 = fmaxf(mx1, __shfl_xor(mx1, m, 64));
    }
    float e0 = EXP2(L2E * (x0 - mx0));
    float e1 = EXP2(L2E * (x1 - mx1));
    float s0 = e0, s1 = e1;
#pragma unroll
    for (int m = 1; m < 64; m <<= 1) {
        s0 += __shfl_xor(s0, m, 64);
        s1 += __shfl_xor(s1, m, 64);
    }
    sls[(wv * 2 + 0) * T_ + lane] = e0 * RCP(s0);
    sls[(wv * 2 + 1) * T_ + lane] = e1 * RCP(s1);
    __syncthreads();

    // emb = weights @ hist ; lane owns d-quad, hist f32 from L1/L2
    int d0 = lane * 4;
    float acc4[2][4] = {};
#pragma unroll 4
    for (int t = 0; t < T_; ++t) {
        float4 h4 = *(const float4*)&histf[t * D_ + d0];
        float w0 = sls[(wv * 2 + 0) * T_ + t];
        float w1 = sls[(wv * 2 + 1) * T_ + t];
        acc4[0][0] = fmaf(w0, h4.x, acc4[0][0]); acc4[0][1] = fmaf(w0, h4.y, acc4[0][1]);
        acc4[0][2] = fmaf(w0, h4.z, acc4[0][2]); acc4[0][3] = fmaf(w0, h4.w, acc4[0][3]);
        acc4[1][0] = fmaf(w1, h4.x, acc4[1][0]); acc4[1][1] = fmaf(w1, h4.y, acc4[1][1]);
        acc4[1][2] = fmaf(w1, h4.z, acc4[1][2]); acc4[1][3] = fmaf(w1, h4.w, acc4[1][3]);
    }
#pragma unroll
    for (int r = 0; r < 2; ++r) {
        size_t row = (size_t)(b0 + wv * 2 + r);
        bool m = get_mask(maskp, mflag, (int)row);
        float4 av = *(const float4*)&accum[row * D_ + d0];
        float4 o;
        o.x = m ? fmaf(av.x, DECAY_, acc4[r][0]) : av.x;
        o.y = m ? fmaf(av.y, DECAY_, acc4[r][1]) : av.y;
        o.z = m ? fmaf(av.z, DECAY_, acc4[r][2]) : av.z;
        o.w = m ? fmaf(av.w, DECAY_, acc4[r][3]) : av.w;
        *(float4*)&out_emb[row * D_ + d0] = o;
    }
}

extern "C" void kernel_launch(void* const* d_in, const int* in_sizes, int n_in,
                              void* d_out, int out_size, void* d_ws, size_t ws_size,
                              hipStream_t stream) {
    const float* features = (const float*)d_in[0];
    const float* h        = (const float*)d_in[1];
    const float* accum    = (const float*)d_in[2];
    const void*  maskp    = d_in[3];
    const float* tokens   = (const float*)d_in[4];
    const float* Wih      = (const float*)d_in[5];
    const float* Whh      = (const float*)d_in[6];
    const float* bih      = (const float*)d_in[7];
    const float* bhh      = (const float*)d_in[8];
    const float* Wh       = (const float*)d_in[9];
    const float* bh       = (const float*)d_in[10];
    const float* Wc       = (const float*)d_in[11];
    const float* bc       = (const float*)d_in[12];
    const float* v        = (const float*)d_in[13];
    // d_in[14] = bv : softmax-invariant, unused

    float* out = (float*)d_out;  // [B*D] emb_out, then [B*D] h_out

    __bf16* Wihb  = (__bf16*)d_ws;                  // 768*128
    __bf16* Whhb  = Wihb + 768 * 128;               // 768*256
    __bf16* Wcb   = Whhb + 768 * 256;               // 256*256
    float*  histf = (float*)(Wcb + 256 * 256);      // 64*256 f32
    __bf16* etp   = (__bf16*)(histf + 64 * 256);    // 64*256 bf16 (packed exp2 of tokp~)
    __bf16* ecb   = etp + 64 * 256;                 // B*256 bf16 (exp2 of ctx~)
    int*    mflag = (int*)(ecb + (size_t)B_ * D_);

    hipLaunchKernelGGL(mask_probe, dim3(1), dim3(256), 0, stream,
                       (const unsigned int*)maskp, mflag);
    hipLaunchKernelGGL(convert_w, dim3(352), dim3(256), 0, stream,
                       Wih, Whh, Wc, Wihb, Whhb, Wcb);
    hipLaunchKernelGGL(prep_kernel, dim3(64), dim3(256), 0, stream,
                       tokens, Wh, bh, histf, etp);
    hipLaunchKernelGGL(gru_fused, dim3(B_ / 32), dim3(256), 0, stream,
                       features, h, maskp, mflag, Wihb, Whhb, Wcb, bih, bhh, bc,
                       out + (size_t)B_ * D_, ecb);
    hipLaunchKernelGGL(attn7, dim3(B_ / 8), dim3(256), 0, stream,
                       ecb, (const unsigned short*)etp, histf, v, accum, maskp, mflag, out);
}